// Round 1
// baseline (1234.885 us; speedup 1.0000x reference)
//
#include <hip/hip_runtime.h>
#include <hip/hip_bf16.h>
#include <stdint.h>

#define N_NODES 50000
#define N_EDGES 800000
#define NL 2

// K strides (bf16 elements): pad +8 over the k-extent to skew LDS banks.
#define KS1 296   // msg GEMM1: K=272 padded to 288 (9 k-steps), stride 296
#define KS2 136   // 128-K GEMMs: 4 k-steps, stride 136
#define KSU 264   // upd GEMM1: K=256 (8 k-steps), stride 264

typedef __bf16 bf16x8 __attribute__((ext_vector_type(8)));
typedef float f32x4 __attribute__((ext_vector_type(4)));

__device__ __forceinline__ f32x4 mfma_bf16(uint4 a, uint4 b, f32x4 c) {
    return __builtin_amdgcn_mfma_f32_16x16x32_bf16(
        __builtin_bit_cast(bf16x8, a), __builtin_bit_cast(bf16x8, b), c, 0, 0, 0);
}

__device__ __forceinline__ unsigned short f2b(float f) {
    union { float f; unsigned u; } v; v.f = f;
    unsigned r = v.u + 0x7FFFu + ((v.u >> 16) & 1u);   // RNE
    return (unsigned short)(r >> 16);
}

// 16(rows-per-wave-tile... actually 16 rows handled as one 16x16 tile) x 128 cols,
// K accumulated over KSTEPS chunks of 32. aLane: LDS ptr pre-offset to
// (m_tile + (lane&15))*Astride + (lane>>4)*8. bLane: global ptr pre-offset to
// (lane&15)*BSTR + (lane>>4)*8 of a [128][BSTR] transposed weight.
template<int KSTEPS, int BSTR>
__device__ __forceinline__ void gemm8(const unsigned short* aLane,
                                      const unsigned short* bLane, f32x4 acc[8]) {
#pragma unroll
    for (int kc = 0; kc < KSTEPS; kc++) {
        uint4 a = *(const uint4*)(aLane + kc * 32);
#pragma unroll
        for (int ct = 0; ct < 8; ct++) {
            uint4 b = *(const uint4*)(bLane + (size_t)ct * 16 * BSTR + kc * 32);
            acc[ct] = mfma_bf16(a, b, acc[ct]);
        }
    }
}

// ---------------- weight prep: transpose + pad + fp32->bf16 ----------------
__global__ void prep_kernel(const float* __restrict__ mW1, const float* __restrict__ mW2,
                            const float* __restrict__ uW1, const float* __restrict__ uW2,
                            const float* __restrict__ hW,
                            unsigned short* __restrict__ w1t, unsigned short* __restrict__ w2t,
                            unsigned short* __restrict__ u1t, unsigned short* __restrict__ u2t,
                            unsigned short* __restrict__ ht) {
    int i = blockIdx.x * 256 + threadIdx.x;
    const int S0 = NL * 128 * KS1;
    const int S1 = NL * 128 * KS2;
    const int S2 = NL * 128 * KSU;
    const int S3 = NL * 128 * KS2;
    const int S4 = 128 * KS2;
    if (i < S0) {
        int l = i / (128 * KS1), r = i % (128 * KS1), n = r / KS1, k = r % KS1;
        w1t[i] = (k < 272) ? f2b(mW1[((size_t)l * 272 + k) * 128 + n]) : (unsigned short)0;
        return;
    }
    i -= S0;
    if (i < S1) {
        int l = i / (128 * KS2), r = i % (128 * KS2), n = r / KS2, k = r % KS2;
        w2t[i] = (k < 128) ? f2b(mW2[((size_t)l * 128 + k) * 128 + n]) : (unsigned short)0;
        return;
    }
    i -= S1;
    if (i < S2) {
        int l = i / (128 * KSU), r = i % (128 * KSU), n = r / KSU, k = r % KSU;
        u1t[i] = (k < 256) ? f2b(uW1[((size_t)l * 256 + k) * 128 + n]) : (unsigned short)0;
        return;
    }
    i -= S2;
    if (i < S3) {
        int l = i / (128 * KS2), r = i % (128 * KS2), n = r / KS2, k = r % KS2;
        u2t[i] = (k < 128) ? f2b(uW2[((size_t)l * 128 + k) * 128 + n]) : (unsigned short)0;
        return;
    }
    i -= S3;
    if (i < S4) {
        int n = i / KS2, k = i % KS2;
        ht[i] = (k < 128) ? f2b(hW[(size_t)k * 128 + n]) : (unsigned short)0;
    }
}

// ---------------- edge_attr fp32 -> bf16 ----------------
__global__ void ea_kernel(const float* __restrict__ ea, unsigned short* __restrict__ eab) {
    int i = blockIdx.x * 256 + threadIdx.x;   // one float4 each; E*16/4 = 3.2M exact
    float4 v = ((const float4*)ea)[i];
    ((ushort4*)eab)[i] = make_ushort4(f2b(v.x), f2b(v.y), f2b(v.z), f2b(v.w));
}

// ---------------- encoder: relu(x@W+b) -> LN ----------------
__global__ __launch_bounds__(256) void enc_kernel(
        const float* __restrict__ x, const float* __restrict__ W,
        const float* __restrict__ b, const float* __restrict__ g, const float* __restrict__ bet,
        float* __restrict__ h, unsigned short* __restrict__ hb) {
    __shared__ float sx[64];
    __shared__ float redS[4], redSS[4];
    const int t = threadIdx.x;
    const int nb = blockIdx.x * 2;           // 2 nodes / 256-thread block; 25000 blocks exact
    if (t < 64) sx[t] = x[(size_t)nb * 32 + t];
    __syncthreads();
    const int half = t >> 7, j = t & 127;
    const int node = nb + half;
    float acc = b[j];
#pragma unroll
    for (int k = 0; k < 32; k++) acc += sx[half * 32 + k] * W[k * 128 + j];
    float v = fmaxf(acc, 0.f);
    float s = v, ss = v * v;
#pragma unroll
    for (int d = 32; d > 0; d >>= 1) { s += __shfl_down(s, d); ss += __shfl_down(ss, d); }
    const int wv = t >> 6;
    if ((t & 63) == 0) { redS[wv] = s; redSS[wv] = ss; }
    __syncthreads();
    float S = redS[half * 2] + redS[half * 2 + 1];
    float SS = redSS[half * 2] + redSS[half * 2 + 1];
    float mu = S * (1.f / 128.f);
    float var = SS * (1.f / 128.f) - mu * mu;
    float rs = rsqrtf(var + 1e-5f);
    float o = (v - mu) * rs * g[j] + bet[j];
    h[(size_t)node * 128 + j] = o;
    hb[(size_t)node * 128 + j] = f2b(o);
}

// ---------------- degree ----------------
__global__ void deg_kernel(const int* __restrict__ tgt, float* __restrict__ cnt) {
    int i = blockIdx.x * 256 + threadIdx.x;
    if (i < N_EDGES) atomicAdd(cnt + tgt[i], 1.0f);
}

// ---------------- message MLP + scatter-add ----------------
__global__ __launch_bounds__(256, 2) void msg_kernel(
        const unsigned short* __restrict__ hb, const unsigned short* __restrict__ eab,
        const int* __restrict__ src, const int* __restrict__ tgt,
        const unsigned short* __restrict__ w1t, const unsigned short* __restrict__ w2t,
        const float* __restrict__ b1, const float* __restrict__ b2,
        float* __restrict__ aggr) {
    __shared__ __align__(16) unsigned short As[64 * KS1];
    __shared__ __align__(16) unsigned short Hs[64 * KS2];
    __shared__ int sTgt[64];

    const int t = threadIdx.x;
    const int e0 = blockIdx.x * 64;          // E = 12500*64 exact
    {
        const int m = t >> 2, q = t & 3;
        const int e = e0 + m;
        const int sn = src[e];
        const int tn = tgt[e];
        if (q == 0) sTgt[m] = tn;
        uint4* dst = (uint4*)(As + m * KS1);
        const uint4* pt = (const uint4*)(hb + (size_t)tn * 128);
        const uint4* ps = (const uint4*)(hb + (size_t)sn * 128);
#pragma unroll
        for (int i = 0; i < 4; i++) dst[q * 4 + i] = pt[q * 4 + i];
        uint4* dst2 = (uint4*)(As + m * KS1 + 128);
#pragma unroll
        for (int i = 0; i < 4; i++) dst2[q * 4 + i] = ps[q * 4 + i];
        if (q == 0) {
            const uint4* pe = (const uint4*)(eab + (size_t)e * 16);
            uint4* de = (uint4*)(As + m * KS1 + 256);
            de[0] = pe[0]; de[1] = pe[1];
        } else if (q == 1) {
            uint4 z{0, 0, 0, 0};
            uint4* dp = (uint4*)(As + m * KS1 + 272);
            dp[0] = z; dp[1] = z; dp[2] = z;
        }
    }
    __syncthreads();

    const int wv = t >> 6, lane = t & 63, lr = lane & 15, lq = lane >> 4;
    const int m0 = wv * 16;
    const f32x4 z4 = {0.f, 0.f, 0.f, 0.f};
    f32x4 acc[8];
#pragma unroll
    for (int i = 0; i < 8; i++) acc[i] = z4;
    gemm8<9, KS1>(As + (m0 + lr) * KS1 + lq * 8, w1t + (size_t)lr * KS1 + lq * 8, acc);
#pragma unroll
    for (int ct = 0; ct < 8; ct++) {
        const int col = ct * 16 + lr;
        const float bv = b1[col];
#pragma unroll
        for (int r = 0; r < 4; r++) {
            float v = fmaxf(acc[ct][r] + bv, 0.f);
            Hs[(m0 + lq * 4 + r) * KS2 + col] = f2b(v);
        }
    }
    __syncthreads();

    f32x4 acc2[8];
#pragma unroll
    for (int i = 0; i < 8; i++) acc2[i] = z4;
    gemm8<4, KS2>(Hs + (m0 + lr) * KS2 + lq * 8, w2t + (size_t)lr * KS2 + lq * 8, acc2);
#pragma unroll
    for (int ct = 0; ct < 8; ct++) {
        const int col = ct * 16 + lr;
        const float bv = b2[col];
#pragma unroll
        for (int r = 0; r < 4; r++) {
            const int ml = m0 + lq * 4 + r;
            atomicAdd(aggr + (size_t)sTgt[ml] * 128 + col, acc2[ct][r] + bv);
        }
    }
}

// ---------------- update MLP + residual + LN ----------------
__global__ __launch_bounds__(256, 2) void upd_kernel(
        const unsigned short* __restrict__ hb_in, const float* __restrict__ h_in,
        const float* __restrict__ aggr, const float* __restrict__ cnt,
        const unsigned short* __restrict__ u1t, const unsigned short* __restrict__ u2t,
        const float* __restrict__ b1, const float* __restrict__ b2,
        const float* __restrict__ g, const float* __restrict__ bet,
        float* __restrict__ h_out, unsigned short* __restrict__ hb_out) {
    __shared__ __align__(16) char smemA[64 * KSU * 2];   // As (bf16) then LNbuf (fp32, stride 132)
    __shared__ __align__(16) unsigned short Hs[64 * KS2];
    unsigned short* As = (unsigned short*)smemA;
    float* LNb = (float*)smemA;

    const int t = threadIdx.x;
    const int n0 = blockIdx.x * 64;
    {
        const int m = t >> 2, q = t & 3;
        const int node = n0 + m;
        unsigned short* row = As + m * KSU;
        if (node < N_NODES) {
            const uint4* ph = (const uint4*)(hb_in + (size_t)node * 128);
            uint4* d0 = (uint4*)row;
#pragma unroll
            for (int i = 0; i < 4; i++) d0[q * 4 + i] = ph[q * 4 + i];
            const float rden = 1.0f / fmaxf(cnt[node], 1.0f);
            const float4* pa = (const float4*)(aggr + (size_t)node * 128 + q * 32);
            ushort4* d1 = (ushort4*)(row + 128 + q * 32);
#pragma unroll
            for (int i = 0; i < 8; i++) {
                float4 v = pa[i];
                d1[i] = make_ushort4(f2b(v.x * rden), f2b(v.y * rden),
                                     f2b(v.z * rden), f2b(v.w * rden));
            }
            if (q == 0) { uint4 z{0, 0, 0, 0}; ((uint4*)(row + 256))[0] = z; }
        } else {
            uint4 z{0, 0, 0, 0};
            uint4* d = (uint4*)row;
            for (int i = q; i < 33; i += 4) d[i] = z;
        }
    }
    __syncthreads();

    const int wv = t >> 6, lane = t & 63, lr = lane & 15, lq = lane >> 4;
    const int m0 = wv * 16;
    const f32x4 z4 = {0.f, 0.f, 0.f, 0.f};
    f32x4 acc[8];
#pragma unroll
    for (int i = 0; i < 8; i++) acc[i] = z4;
    gemm8<8, KSU>(As + (m0 + lr) * KSU + lq * 8, u1t + (size_t)lr * KSU + lq * 8, acc);
#pragma unroll
    for (int ct = 0; ct < 8; ct++) {
        const int col = ct * 16 + lr;
        const float bv = b1[col];
#pragma unroll
        for (int r = 0; r < 4; r++) {
            float v = fmaxf(acc[ct][r] + bv, 0.f);
            Hs[(m0 + lq * 4 + r) * KS2 + col] = f2b(v);
        }
    }
    __syncthreads();

    f32x4 acc2[8];
#pragma unroll
    for (int i = 0; i < 8; i++) acc2[i] = z4;
    gemm8<4, KS2>(Hs + (m0 + lr) * KS2 + lq * 8, u2t + (size_t)lr * KS2 + lq * 8, acc2);

    // residual add into LN staging (overlays As row-for-row; rows are wave-private)
#pragma unroll
    for (int ct = 0; ct < 8; ct++) {
        const int col = ct * 16 + lr;
        const float bv = b2[col];
#pragma unroll
        for (int r = 0; r < 4; r++) {
            const int ml = m0 + lq * 4 + r;
            const int node = n0 + ml;
            if (node < N_NODES)
                LNb[ml * 132 + col] = acc2[ct][r] + bv + h_in[(size_t)node * 128 + col];
        }
    }
    __syncthreads();

    {   // LayerNorm: 4 threads per row
        const int r = t >> 2, c0 = (t & 3) * 32;
        const int node = n0 + r;
        if (node < N_NODES) {
            float s = 0.f, ss = 0.f;
#pragma unroll
            for (int i = 0; i < 32; i++) { float v = LNb[r * 132 + c0 + i]; s += v; ss += v * v; }
            s += __shfl_xor(s, 1); ss += __shfl_xor(ss, 1);
            s += __shfl_xor(s, 2); ss += __shfl_xor(ss, 2);
            const float mu = s * (1.0f / 128.0f);
            const float var = ss * (1.0f / 128.0f) - mu * mu;
            const float rs = rsqrtf(var + 1e-5f);
#pragma unroll
            for (int i = 0; i < 32; i++) {
                const int j = c0 + i;
                float v = (LNb[r * 132 + j] - mu) * rs * g[j] + bet[j];
                h_out[(size_t)node * 128 + j] = v;
                hb_out[(size_t)node * 128 + j] = f2b(v);
            }
        }
    }
}

// ---------------- head GEMM ----------------
__global__ __launch_bounds__(256, 2) void head_kernel(
        const unsigned short* __restrict__ hb, const unsigned short* __restrict__ ht,
        const float* __restrict__ hbias, float* __restrict__ out) {
    __shared__ __align__(16) unsigned short As[64 * KS2];
    const int t = threadIdx.x;
    const int n0 = blockIdx.x * 64;
    {
        const int m = t >> 2, q = t & 3;
        const int node = n0 + m;
        uint4* dst = (uint4*)(As + m * KS2);
        if (node < N_NODES) {
            const uint4* s = (const uint4*)(hb + (size_t)node * 128);
#pragma unroll
            for (int i = 0; i < 4; i++) dst[q * 4 + i] = s[q * 4 + i];
        } else {
            uint4 z{0, 0, 0, 0};
            for (int i = q; i < 16; i += 4) dst[i] = z;
        }
    }
    __syncthreads();

    const int wv = t >> 6, lane = t & 63, lr = lane & 15, lq = lane >> 4;
    const int m0 = wv * 16;
    const f32x4 z4 = {0.f, 0.f, 0.f, 0.f};
    f32x4 acc[8];
#pragma unroll
    for (int i = 0; i < 8; i++) acc[i] = z4;
    gemm8<4, KS2>(As + (m0 + lr) * KS2 + lq * 8, ht + (size_t)lr * KS2 + lq * 8, acc);
#pragma unroll
    for (int ct = 0; ct < 8; ct++) {
        const int col = ct * 16 + lr;
        const float bv = hbias[col];
#pragma unroll
        for (int r = 0; r < 4; r++) {
            const int node = n0 + m0 + lq * 4 + r;
            if (node < N_NODES) out[(size_t)node * 128 + col] = acc[ct][r] + bv;
        }
    }
}

extern "C" void kernel_launch(void* const* d_in, const int* in_sizes, int n_in,
                              void* d_out, int out_size, void* d_ws, size_t ws_size,
                              hipStream_t stream) {
    const float* x       = (const float*)d_in[0];
    const int*   ei      = (const int*)d_in[1];
    const float* ea      = (const float*)d_in[2];
    const float* encW    = (const float*)d_in[3];
    const float* encb    = (const float*)d_in[4];
    const float* encg    = (const float*)d_in[5];
    const float* encbeta = (const float*)d_in[6];
    const float* msgW1   = (const float*)d_in[7];
    const float* msgb1   = (const float*)d_in[8];
    const float* msgW2   = (const float*)d_in[9];
    const float* msgb2   = (const float*)d_in[10];
    const float* updW1   = (const float*)d_in[11];
    const float* updb1   = (const float*)d_in[12];
    const float* updW2   = (const float*)d_in[13];
    const float* updb2   = (const float*)d_in[14];
    const float* lng     = (const float*)d_in[15];
    const float* lnbeta  = (const float*)d_in[16];
    const float* headW   = (const float*)d_in[17];
    const float* headb   = (const float*)d_in[18];

    char* w = (char*)d_ws;
    size_t off = 0;
    auto nxt = [&](size_t bytes) -> void* {
        void* p = w + off;
        off = (off + bytes + 255) & ~(size_t)255;
        return p;
    };
    float*          h    = (float*)nxt((size_t)N_NODES * 128 * 4);
    unsigned short* hb   = (unsigned short*)nxt((size_t)N_NODES * 128 * 2);
    float*          aggr = (float*)nxt((size_t)N_NODES * 128 * 4);
    float*          cnt  = (float*)nxt((size_t)N_NODES * 4);
    unsigned short* eab  = (unsigned short*)nxt((size_t)N_EDGES * 16 * 2);
    unsigned short* w1t  = (unsigned short*)nxt((size_t)NL * 128 * KS1 * 2);
    unsigned short* w2t  = (unsigned short*)nxt((size_t)NL * 128 * KS2 * 2);
    unsigned short* u1t  = (unsigned short*)nxt((size_t)NL * 128 * KSU * 2);
    unsigned short* u2t  = (unsigned short*)nxt((size_t)NL * 128 * KS2 * 2);
    unsigned short* ht   = (unsigned short*)nxt((size_t)128 * KS2 * 2);

    hipMemsetAsync(cnt, 0, (size_t)N_NODES * 4, stream);
    prep_kernel<<<900, 256, 0, stream>>>(msgW1, msgW2, updW1, updW2, headW,
                                         w1t, w2t, u1t, u2t, ht);
    ea_kernel<<<12500, 256, 0, stream>>>(ea, eab);
    enc_kernel<<<25000, 256, 0, stream>>>(x, encW, encb, encg, encbeta, h, hb);
    deg_kernel<<<3125, 256, 0, stream>>>(ei + N_EDGES, cnt);

    for (int l = 0; l < NL; l++) {
        hipMemsetAsync(aggr, 0, (size_t)N_NODES * 128 * 4, stream);
        msg_kernel<<<12500, 256, 0, stream>>>(hb, eab, ei, ei + N_EDGES,
                                              w1t + (size_t)l * 128 * KS1,
                                              w2t + (size_t)l * 128 * KS2,
                                              msgb1 + l * 128, msgb2 + l * 128, aggr);
        upd_kernel<<<782, 256, 0, stream>>>(hb, h, aggr, cnt,
                                            u1t + (size_t)l * 128 * KSU,
                                            u2t + (size_t)l * 128 * KS2,
                                            updb1 + l * 128, updb2 + l * 128,
                                            lng + l * 128, lnbeta + l * 128, h, hb);
    }
    head_kernel<<<782, 256, 0, stream>>>(hb, ht, headb, (float*)d_out);
}

// Round 2
// 1205.817 us; speedup vs baseline: 1.0241x; 1.0241x over previous
//
#include <hip/hip_runtime.h>
#include <hip/hip_bf16.h>
#include <stdint.h>

#define N_NODES 50000
#define N_EDGES 800000
#define NL 2

// K strides (bf16 elements)
#define KS1 296   // msg GEMM1: K=272 padded to 288 (9 k-steps), row stride 296
#define KS2 136   // 128-K GEMMs: 4 k-steps, stride 136
#define KSU 264   // upd GEMM1: K=256 (8 k-steps), stride 264

typedef __bf16 bf16x8 __attribute__((ext_vector_type(8)));
typedef float f32x4 __attribute__((ext_vector_type(4)));

__device__ __forceinline__ f32x4 mfma_bf16(uint4 a, uint4 b, f32x4 c) {
    return __builtin_amdgcn_mfma_f32_16x16x32_bf16(
        __builtin_bit_cast(bf16x8, a), __builtin_bit_cast(bf16x8, b), c, 0, 0, 0);
}

__device__ __forceinline__ unsigned short f2b(float f) {
    union { float f; unsigned u; } v; v.f = f;
    unsigned r = v.u + 0x7FFFu + ((v.u >> 16) & 1u);   // RNE
    return (unsigned short)(r >> 16);
}

// One 16-row wave tile x 128 cols, K over KSTEPS chunks of 32.
// aLane: LDS ptr pre-offset to (row_base+lane&15)*Arowstride + (lane>>4)*8.
// bLane: global ptr pre-offset to (lane&15)*BSTR + (lane>>4)*8 of [128][BSTR] W^T.
template<int KSTEPS, int BSTR>
__device__ __forceinline__ void gemm8(const unsigned short* aLane,
                                      const unsigned short* bLane, f32x4 acc[8]) {
#pragma unroll
    for (int kc = 0; kc < KSTEPS; kc++) {
        uint4 a = *(const uint4*)(aLane + kc * 32);
#pragma unroll
        for (int ct = 0; ct < 8; ct++) {
            uint4 b = *(const uint4*)(bLane + (size_t)ct * 16 * BSTR + kc * 32);
            acc[ct] = mfma_bf16(a, b, acc[ct]);
        }
    }
}

// ---------------- weight prep: transpose + pad + fp32->bf16 ----------------
__global__ void prep_kernel(const float* __restrict__ mW1, const float* __restrict__ mW2,
                            const float* __restrict__ uW1, const float* __restrict__ uW2,
                            const float* __restrict__ hW,
                            unsigned short* __restrict__ w1t, unsigned short* __restrict__ w2t,
                            unsigned short* __restrict__ u1t, unsigned short* __restrict__ u2t,
                            unsigned short* __restrict__ ht) {
    int i = blockIdx.x * 256 + threadIdx.x;
    const int S0 = NL * 128 * KS1;
    const int S1 = NL * 128 * KS2;
    const int S2 = NL * 128 * KSU;
    const int S3 = NL * 128 * KS2;
    const int S4 = 128 * KS2;
    if (i < S0) {
        int l = i / (128 * KS1), r = i % (128 * KS1), n = r / KS1, k = r % KS1;
        w1t[i] = (k < 272) ? f2b(mW1[((size_t)l * 272 + k) * 128 + n]) : (unsigned short)0;
        return;
    }
    i -= S0;
    if (i < S1) {
        int l = i / (128 * KS2), r = i % (128 * KS2), n = r / KS2, k = r % KS2;
        w2t[i] = (k < 128) ? f2b(mW2[((size_t)l * 128 + k) * 128 + n]) : (unsigned short)0;
        return;
    }
    i -= S1;
    if (i < S2) {
        int l = i / (128 * KSU), r = i % (128 * KSU), n = r / KSU, k = r % KSU;
        u1t[i] = (k < 256) ? f2b(uW1[((size_t)l * 256 + k) * 128 + n]) : (unsigned short)0;
        return;
    }
    i -= S2;
    if (i < S3) {
        int l = i / (128 * KS2), r = i % (128 * KS2), n = r / KS2, k = r % KS2;
        u2t[i] = (k < 128) ? f2b(uW2[((size_t)l * 128 + k) * 128 + n]) : (unsigned short)0;
        return;
    }
    i -= S3;
    if (i < S4) {
        int n = i / KS2, k = i % KS2;
        ht[i] = (k < 128) ? f2b(hW[(size_t)k * 128 + n]) : (unsigned short)0;
    }
}

// ---------------- encoder: relu(x@W+b) -> LN ----------------
__global__ __launch_bounds__(256) void enc_kernel(
        const float* __restrict__ x, const float* __restrict__ W,
        const float* __restrict__ b, const float* __restrict__ g, const float* __restrict__ bet,
        float* __restrict__ h, unsigned short* __restrict__ hb) {
    __shared__ float sx[64];
    __shared__ float redS[4], redSS[4];
    const int t = threadIdx.x;
    const int nb = blockIdx.x * 2;           // 2 nodes / block; 25000 blocks exact
    if (t < 64) sx[t] = x[(size_t)nb * 32 + t];
    __syncthreads();
    const int half = t >> 7, j = t & 127;
    const int node = nb + half;
    float acc = b[j];
#pragma unroll
    for (int k = 0; k < 32; k++) acc += sx[half * 32 + k] * W[k * 128 + j];
    float v = fmaxf(acc, 0.f);
    float s = v, ss = v * v;
#pragma unroll
    for (int d = 32; d > 0; d >>= 1) { s += __shfl_down(s, d); ss += __shfl_down(ss, d); }
    const int wv = t >> 6;
    if ((t & 63) == 0) { redS[wv] = s; redSS[wv] = ss; }
    __syncthreads();
    float S = redS[half * 2] + redS[half * 2 + 1];
    float SS = redSS[half * 2] + redSS[half * 2 + 1];
    float mu = S * (1.f / 128.f);
    float var = SS * (1.f / 128.f) - mu * mu;
    float rs = rsqrtf(var + 1e-5f);
    float o = (v - mu) * rs * g[j] + bet[j];
    h[(size_t)node * 128 + j] = o;
    hb[(size_t)node * 128 + j] = f2b(o);
}

// ---------------- counting sort of edges by target ----------------
__global__ void hist_kernel(const int* __restrict__ tgt, int* __restrict__ hist) {
    int i = blockIdx.x * 256 + threadIdx.x;   // E = 3125*256 exact
    atomicAdd(hist + tgt[i], 1);
}

__global__ void scan1_kernel(const int* __restrict__ hist, int* __restrict__ incl,
                             int* __restrict__ blksum) {
    __shared__ int buf[256];
    const int t = threadIdx.x;
    const int i = blockIdx.x * 256 + t;
    int v = (i < N_NODES) ? hist[i] : 0;
    buf[t] = v; __syncthreads();
#pragma unroll
    for (int d = 1; d < 256; d <<= 1) {
        int x = (t >= d) ? buf[t - d] : 0;
        __syncthreads();
        buf[t] += x;
        __syncthreads();
    }
    if (i < N_NODES) incl[i] = buf[t];
    if (t == 255) blksum[blockIdx.x] = buf[255];
}

__global__ void scan2_kernel(int* __restrict__ blksum, int nblk) {
    __shared__ int buf[256];
    const int t = threadIdx.x;
    int v = (t < nblk) ? blksum[t] : 0;
    buf[t] = v; __syncthreads();
#pragma unroll
    for (int d = 1; d < 256; d <<= 1) {
        int x = (t >= d) ? buf[t - d] : 0;
        __syncthreads();
        buf[t] += x;
        __syncthreads();
    }
    if (t < nblk) blksum[t] = buf[t];
}

// incl (inclusive, per-block) -> global exclusive offsets, in place (becomes cursor)
__global__ void scan3_kernel(int* __restrict__ incl, const int* __restrict__ blksum,
                             const int* __restrict__ hist) {
    const int i = blockIdx.x * 256 + threadIdx.x;
    if (i >= N_NODES) return;
    const int b = blockIdx.x;
    const int base = (b > 0) ? blksum[b - 1] : 0;
    incl[i] = incl[i] + base - hist[i];
}

// scatter edges to sorted-by-target order; also gather+convert edge_attr
__global__ void scatter_kernel(const int* __restrict__ src, const int* __restrict__ tgt,
                               const float* __restrict__ ea, int* __restrict__ cursor,
                               unsigned short* __restrict__ sSrc, unsigned short* __restrict__ sTgt,
                               unsigned short* __restrict__ eabS) {
    const int e = blockIdx.x * 256 + threadIdx.x;   // E exact
    const int tg = tgt[e];
    const int p = atomicAdd(cursor + tg, 1);
    sSrc[p] = (unsigned short)src[e];
    sTgt[p] = (unsigned short)tg;
    const float4* s = (const float4*)(ea + (size_t)e * 16);
    ushort4* d = (ushort4*)(eabS + (size_t)p * 16);
#pragma unroll
    for (int i = 0; i < 4; i++) {
        float4 v = s[i];
        d[i] = make_ushort4(f2b(v.x), f2b(v.y), f2b(v.z), f2b(v.w));
    }
}

// ---------------- message MLP + segmented-reduction scatter ----------------
// LDS: As[64][KS1] bf16. Hs (GEMM1 out, bf16[64][128]) overlays As rows
// (wave-private rows, no barrier needed). GEMM2 fp32 out [64][148-dword rows]
// overlays the same region. One barrier before the cross-wave reduction.
__global__ __launch_bounds__(256, 4) void msg_kernel(
        const unsigned short* __restrict__ hb, const unsigned short* __restrict__ eabS,
        const unsigned short* __restrict__ sSrc, const unsigned short* __restrict__ sTgt,
        const unsigned short* __restrict__ w1t, const unsigned short* __restrict__ w2t,
        const float* __restrict__ b1, const float* __restrict__ b2,
        float* __restrict__ aggr) {
    __shared__ __align__(16) unsigned short As[64 * KS1];
    __shared__ int sT[64];

    const int t = threadIdx.x;
    const int e0 = blockIdx.x * 64;          // E = 12500*64 exact
    {
        const int m = t >> 2, q = t & 3;
        const int pos = e0 + m;
        const int sn = sSrc[pos];
        const int tn = sTgt[pos];
        if (q == 0) sT[m] = tn;
        uint4* dst = (uint4*)(As + m * KS1);
        const uint4* pt = (const uint4*)(hb + (size_t)tn * 128);
        const uint4* ps = (const uint4*)(hb + (size_t)sn * 128);
#pragma unroll
        for (int i = 0; i < 4; i++) dst[q * 4 + i] = pt[q * 4 + i];
        uint4* dst2 = (uint4*)(As + m * KS1 + 128);
#pragma unroll
        for (int i = 0; i < 4; i++) dst2[q * 4 + i] = ps[q * 4 + i];
        if (q == 0) {
            const uint4* pe = (const uint4*)(eabS + (size_t)pos * 16);
            uint4* de = (uint4*)(As + m * KS1 + 256);
            de[0] = pe[0]; de[1] = pe[1];
        } else if (q == 1) {
            uint4 z{0, 0, 0, 0};
            uint4* dp = (uint4*)(As + m * KS1 + 272);
            dp[0] = z; dp[1] = z; dp[2] = z;
        }
    }
    __syncthreads();

    const int wv = t >> 6, lane = t & 63, lr = lane & 15, lq = lane >> 4;
    const int m0 = wv * 16;
    const f32x4 z4 = {0.f, 0.f, 0.f, 0.f};
    f32x4 acc[8];
#pragma unroll
    for (int i = 0; i < 8; i++) acc[i] = z4;
    gemm8<9, KS1>(As + (m0 + lr) * KS1 + lq * 8, w1t + (size_t)lr * KS1 + lq * 8, acc);
    // relu+bias -> bf16 Hs, overlaid on this wave's own (now dead) As rows
#pragma unroll
    for (int ct = 0; ct < 8; ct++) {
        const int col = ct * 16 + lr;
        const float bv = b1[col];
#pragma unroll
        for (int r = 0; r < 4; r++) {
            float v = fmaxf(acc[ct][r] + bv, 0.f);
            As[(m0 + lq * 4 + r) * KS1 + col] = f2b(v);
        }
    }
    // per-wave rows only -> no barrier
    f32x4 acc2[8];
#pragma unroll
    for (int i = 0; i < 8; i++) acc2[i] = z4;
    gemm8<4, KS2>(As + (m0 + lr) * KS1 + lq * 8, w2t + (size_t)lr * KS2 + lq * 8, acc2);

    // fp32 message (+bias) overlaid on this wave's own rows (148 dwords/row)
    float* Or = (float*)As;
#pragma unroll
    for (int ct = 0; ct < 8; ct++) {
        const int col = ct * 16 + lr;
        const float bv = b2[col];
#pragma unroll
        for (int r = 0; r < 4; r++)
            Or[(size_t)(m0 + lq * 4 + r) * 148 + col] = acc2[ct][r] + bv;
    }
    __syncthreads();

    // segmented reduction over sorted targets: 2 threads/col (row halves)
    {
        const int c = t >> 1;
        const int rbase = (t & 1) * 32;
        float s = 0.f;
        int cur = sT[rbase];
        for (int i = 0; i < 32; i++) {
            const int rg = rbase + i;
            const int tg = sT[rg];
            if (tg != cur) {
                atomicAdd(aggr + (size_t)cur * 128 + c, s);
                s = 0.f; cur = tg;
            }
            s += Or[(size_t)rg * 148 + c];
        }
        atomicAdd(aggr + (size_t)cur * 128 + c, s);
    }
}

// ---------------- update MLP + residual + LN ----------------
__global__ __launch_bounds__(256, 2) void upd_kernel(
        const unsigned short* __restrict__ hb_in, const float* __restrict__ h_in,
        const float* __restrict__ aggr, const int* __restrict__ hist,
        const unsigned short* __restrict__ u1t, const unsigned short* __restrict__ u2t,
        const float* __restrict__ b1, const float* __restrict__ b2,
        const float* __restrict__ g, const float* __restrict__ bet,
        float* __restrict__ h_out, unsigned short* __restrict__ hb_out) {
    __shared__ __align__(16) char smemA[64 * KSU * 2];   // As (bf16) then LNbuf (fp32, stride 132)
    __shared__ __align__(16) unsigned short Hs[64 * KS2];
    unsigned short* As = (unsigned short*)smemA;
    float* LNb = (float*)smemA;

    const int t = threadIdx.x;
    const int n0 = blockIdx.x * 64;
    {
        const int m = t >> 2, q = t & 3;
        const int node = n0 + m;
        unsigned short* row = As + m * KSU;
        if (node < N_NODES) {
            const uint4* ph = (const uint4*)(hb_in + (size_t)node * 128);
            uint4* d0 = (uint4*)row;
#pragma unroll
            for (int i = 0; i < 4; i++) d0[q * 4 + i] = ph[q * 4 + i];
            const float rden = 1.0f / fmaxf((float)hist[node], 1.0f);
            const float4* pa = (const float4*)(aggr + (size_t)node * 128 + q * 32);
            ushort4* d1 = (ushort4*)(row + 128 + q * 32);
#pragma unroll
            for (int i = 0; i < 8; i++) {
                float4 v = pa[i];
                d1[i] = make_ushort4(f2b(v.x * rden), f2b(v.y * rden),
                                     f2b(v.z * rden), f2b(v.w * rden));
            }
            if (q == 0) { uint4 z{0, 0, 0, 0}; ((uint4*)(row + 256))[0] = z; }
        } else {
            uint4 z{0, 0, 0, 0};
            uint4* d = (uint4*)row;
            for (int i = q; i < 33; i += 4) d[i] = z;
        }
    }
    __syncthreads();

    const int wv = t >> 6, lane = t & 63, lr = lane & 15, lq = lane >> 4;
    const int m0 = wv * 16;
    const f32x4 z4 = {0.f, 0.f, 0.f, 0.f};
    f32x4 acc[8];
#pragma unroll
    for (int i = 0; i < 8; i++) acc[i] = z4;
    gemm8<8, KSU>(As + (m0 + lr) * KSU + lq * 8, u1t + (size_t)lr * KSU + lq * 8, acc);
#pragma unroll
    for (int ct = 0; ct < 8; ct++) {
        const int col = ct * 16 + lr;
        const float bv = b1[col];
#pragma unroll
        for (int r = 0; r < 4; r++) {
            float v = fmaxf(acc[ct][r] + bv, 0.f);
            Hs[(m0 + lq * 4 + r) * KS2 + col] = f2b(v);
        }
    }
    __syncthreads();

    f32x4 acc2[8];
#pragma unroll
    for (int i = 0; i < 8; i++) acc2[i] = z4;
    gemm8<4, KS2>(Hs + (m0 + lr) * KS2 + lq * 8, u2t + (size_t)lr * KS2 + lq * 8, acc2);

    // residual add into LN staging (overlays As; rows are wave-private)
#pragma unroll
    for (int ct = 0; ct < 8; ct++) {
        const int col = ct * 16 + lr;
        const float bv = b2[col];
#pragma unroll
        for (int r = 0; r < 4; r++) {
            const int ml = m0 + lq * 4 + r;
            const int node = n0 + ml;
            if (node < N_NODES)
                LNb[ml * 132 + col] = acc2[ct][r] + bv + h_in[(size_t)node * 128 + col];
        }
    }
    __syncthreads();

    {   // LayerNorm: 4 threads per row
        const int r = t >> 2, c0 = (t & 3) * 32;
        const int node = n0 + r;
        if (node < N_NODES) {
            float s = 0.f, ss = 0.f;
#pragma unroll
            for (int i = 0; i < 32; i++) { float v = LNb[r * 132 + c0 + i]; s += v; ss += v * v; }
            s += __shfl_xor(s, 1); ss += __shfl_xor(ss, 1);
            s += __shfl_xor(s, 2); ss += __shfl_xor(ss, 2);
            const float mu = s * (1.0f / 128.0f);
            const float var = ss * (1.0f / 128.0f) - mu * mu;
            const float rs = rsqrtf(var + 1e-5f);
#pragma unroll
            for (int i = 0; i < 32; i++) {
                const int j = c0 + i;
                float v = (LNb[r * 132 + j] - mu) * rs * g[j] + bet[j];
                h_out[(size_t)node * 128 + j] = v;
                hb_out[(size_t)node * 128 + j] = f2b(v);
            }
        }
    }
}

// ---------------- head GEMM ----------------
__global__ __launch_bounds__(256, 2) void head_kernel(
        const unsigned short* __restrict__ hb, const unsigned short* __restrict__ ht,
        const float* __restrict__ hbias, float* __restrict__ out) {
    __shared__ __align__(16) unsigned short As[64 * KS2];
    const int t = threadIdx.x;
    const int n0 = blockIdx.x * 64;
    {
        const int m = t >> 2, q = t & 3;
        const int node = n0 + m;
        uint4* dst = (uint4*)(As + m * KS2);
        if (node < N_NODES) {
            const uint4* s = (const uint4*)(hb + (size_t)node * 128);
#pragma unroll
            for (int i = 0; i < 4; i++) dst[q * 4 + i] = s[q * 4 + i];
        } else {
            uint4 z{0, 0, 0, 0};
            for (int i = q; i < 16; i += 4) dst[i] = z;
        }
    }
    __syncthreads();

    const int wv = t >> 6, lane = t & 63, lr = lane & 15, lq = lane >> 4;
    const int m0 = wv * 16;
    const f32x4 z4 = {0.f, 0.f, 0.f, 0.f};
    f32x4 acc[8];
#pragma unroll
    for (int i = 0; i < 8; i++) acc[i] = z4;
    gemm8<4, KS2>(As + (m0 + lr) * KS2 + lq * 8, ht + (size_t)lr * KS2 + lq * 8, acc);
#pragma unroll
    for (int ct = 0; ct < 8; ct++) {
        const int col = ct * 16 + lr;
        const float bv = hbias[col];
#pragma unroll
        for (int r = 0; r < 4; r++) {
            const int node = n0 + m0 + lq * 4 + r;
            if (node < N_NODES) out[(size_t)node * 128 + col] = acc[ct][r] + bv;
        }
    }
}

extern "C" void kernel_launch(void* const* d_in, const int* in_sizes, int n_in,
                              void* d_out, int out_size, void* d_ws, size_t ws_size,
                              hipStream_t stream) {
    const float* x       = (const float*)d_in[0];
    const int*   ei      = (const int*)d_in[1];
    const float* ea      = (const float*)d_in[2];
    const float* encW    = (const float*)d_in[3];
    const float* encb    = (const float*)d_in[4];
    const float* encg    = (const float*)d_in[5];
    const float* encbeta = (const float*)d_in[6];
    const float* msgW1   = (const float*)d_in[7];
    const float* msgb1   = (const float*)d_in[8];
    const float* msgW2   = (const float*)d_in[9];
    const float* msgb2   = (const float*)d_in[10];
    const float* updW1   = (const float*)d_in[11];
    const float* updb1   = (const float*)d_in[12];
    const float* updW2   = (const float*)d_in[13];
    const float* updb2   = (const float*)d_in[14];
    const float* lng     = (const float*)d_in[15];
    const float* lnbeta  = (const float*)d_in[16];
    const float* headW   = (const float*)d_in[17];
    const float* headb   = (const float*)d_in[18];

    char* w = (char*)d_ws;
    size_t off = 0;
    auto nxt = [&](size_t bytes) -> void* {
        void* p = w + off;
        off = (off + bytes + 255) & ~(size_t)255;
        return p;
    };
    float*          h     = (float*)nxt((size_t)N_NODES * 128 * 4);
    unsigned short* hb    = (unsigned short*)nxt((size_t)N_NODES * 128 * 2);
    float*          aggr  = (float*)nxt((size_t)N_NODES * 128 * 4);
    unsigned short* eabS  = (unsigned short*)nxt((size_t)N_EDGES * 16 * 2);
    unsigned short* sSrc  = (unsigned short*)nxt((size_t)N_EDGES * 2);
    unsigned short* sTgtS = (unsigned short*)nxt((size_t)N_EDGES * 2);
    int*            hist  = (int*)nxt((size_t)N_NODES * 4);
    int*            incl  = (int*)nxt((size_t)N_NODES * 4);   // becomes cursor
    int*            blksum= (int*)nxt(256 * 4);
    unsigned short* w1t   = (unsigned short*)nxt((size_t)NL * 128 * KS1 * 2);
    unsigned short* w2t   = (unsigned short*)nxt((size_t)NL * 128 * KS2 * 2);
    unsigned short* u1t   = (unsigned short*)nxt((size_t)NL * 128 * KSU * 2);
    unsigned short* u2t   = (unsigned short*)nxt((size_t)NL * 128 * KS2 * 2);
    unsigned short* ht    = (unsigned short*)nxt((size_t)128 * KS2 * 2);

    const int NBLK = (N_NODES + 255) / 256;   // 196

    hipMemsetAsync(hist, 0, (size_t)N_NODES * 4, stream);
    prep_kernel<<<900, 256, 0, stream>>>(msgW1, msgW2, updW1, updW2, headW,
                                         w1t, w2t, u1t, u2t, ht);
    enc_kernel<<<25000, 256, 0, stream>>>(x, encW, encb, encg, encbeta, h, hb);
    hist_kernel<<<3125, 256, 0, stream>>>(ei + N_EDGES, hist);
    scan1_kernel<<<NBLK, 256, 0, stream>>>(hist, incl, blksum);
    scan2_kernel<<<1, 256, 0, stream>>>(blksum, NBLK);
    scan3_kernel<<<NBLK, 256, 0, stream>>>(incl, blksum, hist);
    scatter_kernel<<<3125, 256, 0, stream>>>(ei, ei + N_EDGES, ea, incl,
                                             sSrc, sTgtS, eabS);

    for (int l = 0; l < NL; l++) {
        hipMemsetAsync(aggr, 0, (size_t)N_NODES * 128 * 4, stream);
        msg_kernel<<<12500, 256, 0, stream>>>(hb, eabS, sSrc, sTgtS,
                                              w1t + (size_t)l * 128 * KS1,
                                              w2t + (size_t)l * 128 * KS2,
                                              msgb1 + l * 128, msgb2 + l * 128, aggr);
        upd_kernel<<<782, 256, 0, stream>>>(hb, h, aggr, hist,
                                            u1t + (size_t)l * 128 * KSU,
                                            u2t + (size_t)l * 128 * KS2,
                                            updb1 + l * 128, updb2 + l * 128,
                                            lng + l * 128, lnbeta + l * 128, h, hb);
    }
    head_kernel<<<782, 256, 0, stream>>>(hb, ht, headb, (float*)d_out);
}

// Round 3
// 677.489 us; speedup vs baseline: 1.8227x; 1.7798x over previous
//
#include <hip/hip_runtime.h>
#include <hip/hip_bf16.h>
#include <stdint.h>

#define N_NODES 50000
#define N_EDGES 800000
#define NL 2

// K strides (bf16 elements)
#define KS1 296   // msg GEMM1: K=272 padded to 288 (9 k-steps), row stride 296
#define KS2 136   // 128-K GEMMs: 4 k-steps, stride 136
#define KSU 264   // upd GEMM1: K=256 (8 k-steps), stride 264

typedef __bf16 bf16x8 __attribute__((ext_vector_type(8)));
typedef float f32x4 __attribute__((ext_vector_type(4)));

__device__ __forceinline__ f32x4 mfma_bf16(uint4 a, uint4 b, f32x4 c) {
    return __builtin_amdgcn_mfma_f32_16x16x32_bf16(
        __builtin_bit_cast(bf16x8, a), __builtin_bit_cast(bf16x8, b), c, 0, 0, 0);
}

__device__ __forceinline__ unsigned short f2b(float f) {
    union { float f; unsigned u; } v; v.f = f;
    unsigned r = v.u + 0x7FFFu + ((v.u >> 16) & 1u);   // RNE
    return (unsigned short)(r >> 16);
}

// Old per-wave 16-row x 128-col tile (kept for head_kernel).
template<int KSTEPS, int BSTR>
__device__ __forceinline__ void gemm8(const unsigned short* aLane,
                                      const unsigned short* bLane, f32x4 acc[8]) {
#pragma unroll
    for (int kc = 0; kc < KSTEPS; kc++) {
        uint4 a = *(const uint4*)(aLane + kc * 32);
#pragma unroll
        for (int ct = 0; ct < 8; ct++) {
            uint4 b = *(const uint4*)(bLane + (size_t)ct * 16 * BSTR + kc * 32);
            acc[ct] = mfma_bf16(a, b, acc[ct]);
        }
    }
}

// Column-split wave tile: 64 rows (4 row-tiles) x 32 cols (2 ct) per wave.
// B fragments are register-reused across the 4 row-tiles -> 4x less B traffic.
// aLane: LDS base + lr*ASTR + lq*8 (row-tile offset rt*16*ASTR added inside).
// bLane: W^T + (colbase+lr)*BSTR + lq*8 (ct offset 16*BSTR added inside).
template<int KSTEPS, int ASTR, int BSTR>
__device__ __forceinline__ void gemm_2x4(const unsigned short* aLane,
                                         const unsigned short* bLane,
                                         f32x4 acc[4][2]) {
#pragma unroll
    for (int kc = 0; kc < KSTEPS; kc++) {
        uint4 b0 = *(const uint4*)(bLane + kc * 32);
        uint4 b1 = *(const uint4*)(bLane + (size_t)16 * BSTR + kc * 32);
#pragma unroll
        for (int rt = 0; rt < 4; rt++) {
            uint4 a = *(const uint4*)(aLane + (size_t)rt * 16 * ASTR + kc * 32);
            acc[rt][0] = mfma_bf16(a, b0, acc[rt][0]);
            acc[rt][1] = mfma_bf16(a, b1, acc[rt][1]);
        }
    }
}

// ---------------- weight prep: transpose + pad + fp32->bf16 ----------------
__global__ void prep_kernel(const float* __restrict__ mW1, const float* __restrict__ mW2,
                            const float* __restrict__ uW1, const float* __restrict__ uW2,
                            const float* __restrict__ hW,
                            unsigned short* __restrict__ w1t, unsigned short* __restrict__ w2t,
                            unsigned short* __restrict__ u1t, unsigned short* __restrict__ u2t,
                            unsigned short* __restrict__ ht) {
    int i = blockIdx.x * 256 + threadIdx.x;
    const int S0 = NL * 128 * KS1;
    const int S1 = NL * 128 * KS2;
    const int S2 = NL * 128 * KSU;
    const int S3 = NL * 128 * KS2;
    const int S4 = 128 * KS2;
    if (i < S0) {
        int l = i / (128 * KS1), r = i % (128 * KS1), n = r / KS1, k = r % KS1;
        w1t[i] = (k < 272) ? f2b(mW1[((size_t)l * 272 + k) * 128 + n]) : (unsigned short)0;
        return;
    }
    i -= S0;
    if (i < S1) {
        int l = i / (128 * KS2), r = i % (128 * KS2), n = r / KS2, k = r % KS2;
        w2t[i] = (k < 128) ? f2b(mW2[((size_t)l * 128 + k) * 128 + n]) : (unsigned short)0;
        return;
    }
    i -= S1;
    if (i < S2) {
        int l = i / (128 * KSU), r = i % (128 * KSU), n = r / KSU, k = r % KSU;
        u1t[i] = (k < 256) ? f2b(uW1[((size_t)l * 256 + k) * 128 + n]) : (unsigned short)0;
        return;
    }
    i -= S2;
    if (i < S3) {
        int l = i / (128 * KS2), r = i % (128 * KS2), n = r / KS2, k = r % KS2;
        u2t[i] = (k < 128) ? f2b(uW2[((size_t)l * 128 + k) * 128 + n]) : (unsigned short)0;
        return;
    }
    i -= S3;
    if (i < S4) {
        int n = i / KS2, k = i % KS2;
        ht[i] = (k < 128) ? f2b(hW[(size_t)k * 128 + n]) : (unsigned short)0;
    }
}

// ---------------- encoder: relu(x@W+b) -> LN ----------------
__global__ __launch_bounds__(256) void enc_kernel(
        const float* __restrict__ x, const float* __restrict__ W,
        const float* __restrict__ b, const float* __restrict__ g, const float* __restrict__ bet,
        float* __restrict__ h, unsigned short* __restrict__ hb) {
    __shared__ float sx[64];
    __shared__ float redS[4], redSS[4];
    const int t = threadIdx.x;
    const int nb = blockIdx.x * 2;           // 2 nodes / block; 25000 blocks exact
    if (t < 64) sx[t] = x[(size_t)nb * 32 + t];
    __syncthreads();
    const int half = t >> 7, j = t & 127;
    const int node = nb + half;
    float acc = b[j];
#pragma unroll
    for (int k = 0; k < 32; k++) acc += sx[half * 32 + k] * W[k * 128 + j];
    float v = fmaxf(acc, 0.f);
    float s = v, ss = v * v;
#pragma unroll
    for (int d = 32; d > 0; d >>= 1) { s += __shfl_down(s, d); ss += __shfl_down(ss, d); }
    const int wv = t >> 6;
    if ((t & 63) == 0) { redS[wv] = s; redSS[wv] = ss; }
    __syncthreads();
    float S = redS[half * 2] + redS[half * 2 + 1];
    float SS = redSS[half * 2] + redSS[half * 2 + 1];
    float mu = S * (1.f / 128.f);
    float var = SS * (1.f / 128.f) - mu * mu;
    float rs = rsqrtf(var + 1e-5f);
    float o = (v - mu) * rs * g[j] + bet[j];
    h[(size_t)node * 128 + j] = o;
    hb[(size_t)node * 128 + j] = f2b(o);
}

// ---------------- counting sort of edges by target ----------------
__global__ void hist_kernel(const int* __restrict__ tgt, int* __restrict__ hist) {
    int i = blockIdx.x * 256 + threadIdx.x;   // E = 3125*256 exact
    atomicAdd(hist + tgt[i], 1);
}

__global__ void scan1_kernel(const int* __restrict__ hist, int* __restrict__ incl,
                             int* __restrict__ blksum) {
    __shared__ int buf[256];
    const int t = threadIdx.x;
    const int i = blockIdx.x * 256 + t;
    int v = (i < N_NODES) ? hist[i] : 0;
    buf[t] = v; __syncthreads();
#pragma unroll
    for (int d = 1; d < 256; d <<= 1) {
        int x = (t >= d) ? buf[t - d] : 0;
        __syncthreads();
        buf[t] += x;
        __syncthreads();
    }
    if (i < N_NODES) incl[i] = buf[t];
    if (t == 255) blksum[blockIdx.x] = buf[255];
}

__global__ void scan2_kernel(int* __restrict__ blksum, int nblk) {
    __shared__ int buf[256];
    const int t = threadIdx.x;
    int v = (t < nblk) ? blksum[t] : 0;
    buf[t] = v; __syncthreads();
#pragma unroll
    for (int d = 1; d < 256; d <<= 1) {
        int x = (t >= d) ? buf[t - d] : 0;
        __syncthreads();
        buf[t] += x;
        __syncthreads();
    }
    if (t < nblk) blksum[t] = buf[t];
}

__global__ void scan3_kernel(int* __restrict__ incl, const int* __restrict__ blksum,
                             const int* __restrict__ hist) {
    const int i = blockIdx.x * 256 + threadIdx.x;
    if (i >= N_NODES) return;
    const int b = blockIdx.x;
    const int base = (b > 0) ? blksum[b - 1] : 0;
    incl[i] = incl[i] + base - hist[i];
}

__global__ void scatter_kernel(const int* __restrict__ src, const int* __restrict__ tgt,
                               const float* __restrict__ ea, int* __restrict__ cursor,
                               unsigned short* __restrict__ sSrc, unsigned short* __restrict__ sTgt,
                               unsigned short* __restrict__ eabS) {
    const int e = blockIdx.x * 256 + threadIdx.x;   // E exact
    const int tg = tgt[e];
    const int p = atomicAdd(cursor + tg, 1);
    sSrc[p] = (unsigned short)src[e];
    sTgt[p] = (unsigned short)tg;
    const float4* s = (const float4*)(ea + (size_t)e * 16);
    ushort4* d = (ushort4*)(eabS + (size_t)p * 16);
#pragma unroll
    for (int i = 0; i < 4; i++) {
        float4 v = s[i];
        d[i] = make_ushort4(f2b(v.x), f2b(v.y), f2b(v.z), f2b(v.w));
    }
}

// ---------------- message MLP + segmented-reduction scatter ----------------
// Column-split waves: wave w owns cols [w*32, w*32+32) for ALL 64 rows.
// Phase layout of the single 37888-B As buffer:
//   stage:  bf16 [64][KS1]   (input, K=272+pad)
//   G1 out: bf16 [64][KS1] cols 0..127 (Hs, overlaid after barrier)
//   G2 out: fp32 [64][148]   (Or, overlaid after barrier; 148*4 == KS1*2)
__global__ __launch_bounds__(256, 4) void msg_kernel(
        const unsigned short* __restrict__ hb, const unsigned short* __restrict__ eabS,
        const unsigned short* __restrict__ sSrc, const unsigned short* __restrict__ sTgt,
        const unsigned short* __restrict__ w1t, const unsigned short* __restrict__ w2t,
        const float* __restrict__ b1, const float* __restrict__ b2,
        float* __restrict__ aggr) {
    __shared__ __align__(16) unsigned short As[64 * KS1];
    __shared__ int sT[64];

    const int t = threadIdx.x;
    const int e0 = blockIdx.x * 64;          // E = 12500*64 exact
    {
        const int m = t >> 2, q = t & 3;
        const int pos = e0 + m;
        const int sn = sSrc[pos];
        const int tn = sTgt[pos];
        if (q == 0) sT[m] = tn;
        uint4* dst = (uint4*)(As + m * KS1);
        const uint4* pt = (const uint4*)(hb + (size_t)tn * 128);
        const uint4* ps = (const uint4*)(hb + (size_t)sn * 128);
#pragma unroll
        for (int i = 0; i < 4; i++) dst[q * 4 + i] = pt[q * 4 + i];
        uint4* dst2 = (uint4*)(As + m * KS1 + 128);
#pragma unroll
        for (int i = 0; i < 4; i++) dst2[q * 4 + i] = ps[q * 4 + i];
        if (q == 0) {
            const uint4* pe = (const uint4*)(eabS + (size_t)pos * 16);
            uint4* de = (uint4*)(As + m * KS1 + 256);
            de[0] = pe[0]; de[1] = pe[1];
        } else if (q == 1) {
            uint4 z{0, 0, 0, 0};
            uint4* dp = (uint4*)(As + m * KS1 + 272);
            dp[0] = z; dp[1] = z; dp[2] = z;
        }
    }
    __syncthreads();

    const int wv = t >> 6, lane = t & 63, lr = lane & 15, lq = lane >> 4;
    const int cb = wv * 32;                  // this wave's column base
    const f32x4 z4 = {0.f, 0.f, 0.f, 0.f};

    f32x4 acc[4][2];
#pragma unroll
    for (int i = 0; i < 4; i++) { acc[i][0] = z4; acc[i][1] = z4; }
    gemm_2x4<9, KS1, KS1>(As + lr * KS1 + lq * 8,
                          w1t + (size_t)(cb + lr) * KS1 + lq * 8, acc);
    __syncthreads();                         // all GEMM1 reads of As complete

    // bias+relu -> bf16 Hs, overlaid on As cols 0..127 (stride KS1)
#pragma unroll
    for (int ct = 0; ct < 2; ct++) {
        const int col = cb + ct * 16 + lr;
        const float bv = b1[col];
#pragma unroll
        for (int rt = 0; rt < 4; rt++) {
#pragma unroll
            for (int r = 0; r < 4; r++) {
                float v = fmaxf(acc[rt][ct][r] + bv, 0.f);
                As[(rt * 16 + lq * 4 + r) * KS1 + col] = f2b(v);
            }
        }
    }
    __syncthreads();

    f32x4 acc2[4][2];
#pragma unroll
    for (int i = 0; i < 4; i++) { acc2[i][0] = z4; acc2[i][1] = z4; }
    gemm_2x4<4, KS1, KS2>(As + lr * KS1 + lq * 8,
                          w2t + (size_t)(cb + lr) * KS2 + lq * 8, acc2);
    __syncthreads();                         // all GEMM2 reads complete

    // fp32 message (+bias) overlaid as [64][148] dwords
    float* Or = (float*)As;
#pragma unroll
    for (int ct = 0; ct < 2; ct++) {
        const int col = cb + ct * 16 + lr;
        const float bv = b2[col];
#pragma unroll
        for (int rt = 0; rt < 4; rt++) {
#pragma unroll
            for (int r = 0; r < 4; r++)
                Or[(size_t)(rt * 16 + lq * 4 + r) * 148 + col] = acc2[rt][ct][r] + bv;
        }
    }
    __syncthreads();

    // segmented reduction over sorted targets: 2 threads/col (row halves)
    {
        const int c = t >> 1;
        const int rbase = (t & 1) * 32;
        float s = 0.f;
        int cur = sT[rbase];
        for (int i = 0; i < 32; i++) {
            const int rg = rbase + i;
            const int tg = sT[rg];
            if (tg != cur) {
                atomicAdd(aggr + (size_t)cur * 128 + c, s);
                s = 0.f; cur = tg;
            }
            s += Or[(size_t)rg * 148 + c];
        }
        atomicAdd(aggr + (size_t)cur * 128 + c, s);
    }
}

// ---------------- update MLP + residual + LN ----------------
// Same column-split structure. Single 33792-B buffer:
//   stage: bf16 [64][KSU]; Hs overlaid cols 0..127 (stride KSU);
//   LN buf: fp32 [64][132] (132*4 == KSU*2).
__global__ __launch_bounds__(256, 4) void upd_kernel(
        const unsigned short* __restrict__ hb_in, const float* __restrict__ h_in,
        const float* __restrict__ aggr, const int* __restrict__ hist,
        const unsigned short* __restrict__ u1t, const unsigned short* __restrict__ u2t,
        const float* __restrict__ b1, const float* __restrict__ b2,
        const float* __restrict__ g, const float* __restrict__ bet,
        float* __restrict__ h_out, unsigned short* __restrict__ hb_out) {
    __shared__ __align__(16) char smemA[64 * KSU * 2];
    unsigned short* As = (unsigned short*)smemA;
    float* LNb = (float*)smemA;

    const int t = threadIdx.x;
    const int n0 = blockIdx.x * 64;
    {
        const int m = t >> 2, q = t & 3;
        const int node = n0 + m;
        unsigned short* row = As + m * KSU;
        if (node < N_NODES) {
            const uint4* ph = (const uint4*)(hb_in + (size_t)node * 128);
            uint4* d0 = (uint4*)row;
#pragma unroll
            for (int i = 0; i < 4; i++) d0[q * 4 + i] = ph[q * 4 + i];
            const float rden = 1.0f / fmaxf((float)hist[node], 1.0f);
            const float4* pa = (const float4*)(aggr + (size_t)node * 128 + q * 32);
            ushort4* d1 = (ushort4*)(row + 128 + q * 32);
#pragma unroll
            for (int i = 0; i < 8; i++) {
                float4 v = pa[i];
                d1[i] = make_ushort4(f2b(v.x * rden), f2b(v.y * rden),
                                     f2b(v.z * rden), f2b(v.w * rden));
            }
            if (q == 0) { uint4 z{0, 0, 0, 0}; ((uint4*)(row + 256))[0] = z; }
        } else {
            uint4 z{0, 0, 0, 0};
            uint4* d = (uint4*)row;
            for (int i = q; i < 33; i += 4) d[i] = z;
        }
    }
    __syncthreads();

    const int wv = t >> 6, lane = t & 63, lr = lane & 15, lq = lane >> 4;
    const int cb = wv * 32;
    const f32x4 z4 = {0.f, 0.f, 0.f, 0.f};

    f32x4 acc[4][2];
#pragma unroll
    for (int i = 0; i < 4; i++) { acc[i][0] = z4; acc[i][1] = z4; }
    gemm_2x4<8, KSU, KSU>(As + lr * KSU + lq * 8,
                          u1t + (size_t)(cb + lr) * KSU + lq * 8, acc);
    __syncthreads();

#pragma unroll
    for (int ct = 0; ct < 2; ct++) {
        const int col = cb + ct * 16 + lr;
        const float bv = b1[col];
#pragma unroll
        for (int rt = 0; rt < 4; rt++) {
#pragma unroll
            for (int r = 0; r < 4; r++) {
                float v = fmaxf(acc[rt][ct][r] + bv, 0.f);
                As[(rt * 16 + lq * 4 + r) * KSU + col] = f2b(v);
            }
        }
    }
    __syncthreads();

    f32x4 acc2[4][2];
#pragma unroll
    for (int i = 0; i < 4; i++) { acc2[i][0] = z4; acc2[i][1] = z4; }
    gemm_2x4<4, KSU, KS2>(As + lr * KSU + lq * 8,
                          u2t + (size_t)(cb + lr) * KS2 + lq * 8, acc2);
    __syncthreads();

    // residual add into LN staging fp32 [64][132]
#pragma unroll
    for (int ct = 0; ct < 2; ct++) {
        const int col = cb + ct * 16 + lr;
        const float bv = b2[col];
#pragma unroll
        for (int rt = 0; rt < 4; rt++) {
#pragma unroll
            for (int r = 0; r < 4; r++) {
                const int ml = rt * 16 + lq * 4 + r;
                const int node = n0 + ml;
                if (node < N_NODES)
                    LNb[ml * 132 + col] = acc2[rt][ct][r] + bv + h_in[(size_t)node * 128 + col];
            }
        }
    }
    __syncthreads();

    {   // LayerNorm: 4 threads per row
        const int r = t >> 2, c0 = (t & 3) * 32;
        const int node = n0 + r;
        if (node < N_NODES) {
            float s = 0.f, ss = 0.f;
#pragma unroll
            for (int i = 0; i < 32; i++) { float v = LNb[r * 132 + c0 + i]; s += v; ss += v * v; }
            s += __shfl_xor(s, 1); ss += __shfl_xor(ss, 1);
            s += __shfl_xor(s, 2); ss += __shfl_xor(ss, 2);
            const float mu = s * (1.0f / 128.0f);
            const float var = ss * (1.0f / 128.0f) - mu * mu;
            const float rs = rsqrtf(var + 1e-5f);
#pragma unroll
            for (int i = 0; i < 32; i++) {
                const int j = c0 + i;
                float v = (LNb[r * 132 + j] - mu) * rs * g[j] + bet[j];
                h_out[(size_t)node * 128 + j] = v;
                hb_out[(size_t)node * 128 + j] = f2b(v);
            }
        }
    }
}

// ---------------- head GEMM ----------------
__global__ __launch_bounds__(256, 2) void head_kernel(
        const unsigned short* __restrict__ hb, const unsigned short* __restrict__ ht,
        const float* __restrict__ hbias, float* __restrict__ out) {
    __shared__ __align__(16) unsigned short As[64 * KS2];
    const int t = threadIdx.x;
    const int n0 = blockIdx.x * 64;
    {
        const int m = t >> 2, q = t & 3;
        const int node = n0 + m;
        uint4* dst = (uint4*)(As + m * KS2);
        if (node < N_NODES) {
            const uint4* s = (const uint4*)(hb + (size_t)node * 128);
#pragma unroll
            for (int i = 0; i < 4; i++) dst[q * 4 + i] = s[q * 4 + i];
        } else {
            uint4 z{0, 0, 0, 0};
            for (int i = q; i < 16; i += 4) dst[i] = z;
        }
    }
    __syncthreads();

    const int wv = t >> 6, lane = t & 63, lr = lane & 15, lq = lane >> 4;
    const int m0 = wv * 16;
    const f32x4 z4 = {0.f, 0.f, 0.f, 0.f};
    f32x4 acc[8];
#pragma unroll
    for (int i = 0; i < 8; i++) acc[i] = z4;
    gemm8<4, KS2>(As + (m0 + lr) * KS2 + lq * 8, ht + (size_t)lr * KS2 + lq * 8, acc);
#pragma unroll
    for (int ct = 0; ct < 8; ct++) {
        const int col = ct * 16 + lr;
        const float bv = hbias[col];
#pragma unroll
        for (int r = 0; r < 4; r++) {
            const int node = n0 + m0 + lq * 4 + r;
            if (node < N_NODES) out[(size_t)node * 128 + col] = acc[ct][r] + bv;
        }
    }
}

extern "C" void kernel_launch(void* const* d_in, const int* in_sizes, int n_in,
                              void* d_out, int out_size, void* d_ws, size_t ws_size,
                              hipStream_t stream) {
    const float* x       = (const float*)d_in[0];
    const int*   ei      = (const int*)d_in[1];
    const float* ea      = (const float*)d_in[2];
    const float* encW    = (const float*)d_in[3];
    const float* encb    = (const float*)d_in[4];
    const float* encg    = (const float*)d_in[5];
    const float* encbeta = (const float*)d_in[6];
    const float* msgW1   = (const float*)d_in[7];
    const float* msgb1   = (const float*)d_in[8];
    const float* msgW2   = (const float*)d_in[9];
    const float* msgb2   = (const float*)d_in[10];
    const float* updW1   = (const float*)d_in[11];
    const float* updb1   = (const float*)d_in[12];
    const float* updW2   = (const float*)d_in[13];
    const float* updb2   = (const float*)d_in[14];
    const float* lng     = (const float*)d_in[15];
    const float* lnbeta  = (const float*)d_in[16];
    const float* headW   = (const float*)d_in[17];
    const float* headb   = (const float*)d_in[18];

    char* w = (char*)d_ws;
    size_t off = 0;
    auto nxt = [&](size_t bytes) -> void* {
        void* p = w + off;
        off = (off + bytes + 255) & ~(size_t)255;
        return p;
    };
    float*          h     = (float*)nxt((size_t)N_NODES * 128 * 4);
    unsigned short* hb    = (unsigned short*)nxt((size_t)N_NODES * 128 * 2);
    float*          aggr  = (float*)nxt((size_t)N_NODES * 128 * 4);
    unsigned short* eabS  = (unsigned short*)nxt((size_t)N_EDGES * 16 * 2);
    unsigned short* sSrc  = (unsigned short*)nxt((size_t)N_EDGES * 2);
    unsigned short* sTgtS = (unsigned short*)nxt((size_t)N_EDGES * 2);
    int*            hist  = (int*)nxt((size_t)N_NODES * 4);
    int*            incl  = (int*)nxt((size_t)N_NODES * 4);   // becomes cursor
    int*            blksum= (int*)nxt(256 * 4);
    unsigned short* w1t   = (unsigned short*)nxt((size_t)NL * 128 * KS1 * 2);
    unsigned short* w2t   = (unsigned short*)nxt((size_t)NL * 128 * KS2 * 2);
    unsigned short* u1t   = (unsigned short*)nxt((size_t)NL * 128 * KSU * 2);
    unsigned short* u2t   = (unsigned short*)nxt((size_t)NL * 128 * KS2 * 2);
    unsigned short* ht    = (unsigned short*)nxt((size_t)128 * KS2 * 2);

    const int NBLK = (N_NODES + 255) / 256;   // 196

    hipMemsetAsync(hist, 0, (size_t)N_NODES * 4, stream);
    prep_kernel<<<900, 256, 0, stream>>>(msgW1, msgW2, updW1, updW2, headW,
                                         w1t, w2t, u1t, u2t, ht);
    enc_kernel<<<25000, 256, 0, stream>>>(x, encW, encb, encg, encbeta, h, hb);
    hist_kernel<<<3125, 256, 0, stream>>>(ei + N_EDGES, hist);
    scan1_kernel<<<NBLK, 256, 0, stream>>>(hist, incl, blksum);
    scan2_kernel<<<1, 256, 0, stream>>>(blksum, NBLK);
    scan3_kernel<<<NBLK, 256, 0, stream>>>(incl, blksum, hist);
    scatter_kernel<<<3125, 256, 0, stream>>>(ei, ei + N_EDGES, ea, incl,
                                             sSrc, sTgtS, eabS);

    for (int l = 0; l < NL; l++) {
        hipMemsetAsync(aggr, 0, (size_t)N_NODES * 128 * 4, stream);
        msg_kernel<<<12500, 256, 0, stream>>>(hb, eabS, sSrc, sTgtS,
                                              w1t + (size_t)l * 128 * KS1,
                                              w2t + (size_t)l * 128 * KS2,
                                              msgb1 + l * 128, msgb2 + l * 128, aggr);
        upd_kernel<<<782, 256, 0, stream>>>(hb, h, aggr, hist,
                                            u1t + (size_t)l * 128 * KSU,
                                            u2t + (size_t)l * 128 * KS2,
                                            updb1 + l * 128, updb2 + l * 128,
                                            lng + l * 128, lnbeta + l * 128, h, hb);
    }
    head_kernel<<<782, 256, 0, stream>>>(hb, ht, headb, (float*)d_out);
}